// Round 8
// baseline (591.903 us; speedup 1.0000x reference)
//
#include <hip/hip_runtime.h>
#include <hip/hip_bf16.h>
#include <math.h>

// Problem constants (fixed by the reference)
#define N_NODES 100000
#define N_EDGES 1600000
#define NFEAT 128
#define NHID  64
#define NCLASS 40
#define NL 6

#define NBUK 256          // coarse buckets for CSR build
#define RPB  391          // rows per bucket (391*256 >= 100000)
#define EPP  (N_EDGES / NBUK)  // 6250 edges per partition block (exact)
#define EP_PAD 256        // zero-padded ep tail for predicated spmm reads
#define NTILES (N_NODES / 16)  // 6250 row-tiles, exact

typedef __attribute__((ext_vector_type(8))) short short8;
typedef __attribute__((ext_vector_type(8))) unsigned short ushort8v;
typedef __attribute__((ext_vector_type(4))) float floatx4;

__device__ __forceinline__ float bfbits(unsigned short u) {
  return __uint_as_float((unsigned int)u << 16);
}
__device__ __forceinline__ short f2bs(float f) {
  __hip_bfloat16 h = __float2bfloat16(f);  // RNE
  return *reinterpret_cast<short*>(&h);
}

// ---------------------------------------------------------------------------
// CSR build (R4 full-line-write design, 1024-thread blocks — proven)
// ---------------------------------------------------------------------------
__global__ __launch_bounds__(1024) void p0_hist_k(const int* __restrict__ row,
                                                  int* __restrict__ h2d) {
  __shared__ int h[NBUK];
  const int i = blockIdx.x, t = threadIdx.x;
  if (t < NBUK) h[t] = 0;
  __syncthreads();
  const int e0 = i * EPP, e1 = e0 + EPP;
  for (int e = e0 + t; e < e1; e += 1024) atomicAdd(&h[row[e] / RPB], 1);
  __syncthreads();
  if (t < NBUK) h2d[i * NBUK + t] = h[t];  // coalesced
}

__global__ __launch_bounds__(256) void k1_scanb_k(int* __restrict__ h2d,
                                                  int* __restrict__ btot) {
  __shared__ int sd[256];
  const int b = blockIdx.x, t = threadIdx.x;
  int v = h2d[t * NBUK + b];
  sd[t] = v;
  __syncthreads();
  for (int off = 1; off < 256; off <<= 1) {
    int a = (t >= off) ? sd[t - off] : 0;
    __syncthreads();
    sd[t] += a;
    __syncthreads();
  }
  h2d[t * NBUK + b] = sd[t] - v;  // exclusive prefix within bucket
  if (t == 255) btot[b] = sd[255];
}

__global__ __launch_bounds__(256) void k2_scanbase_k(const int* __restrict__ btot,
                                                     int* __restrict__ bbase,
                                                     int2* __restrict__ ep) {
  __shared__ int sd[256];
  const int t = threadIdx.x;
  int v = btot[t];
  sd[t] = v;
  __syncthreads();
  for (int off = 1; off < 256; off <<= 1) {
    int a = (t >= off) ? sd[t - off] : 0;
    __syncthreads();
    sd[t] += a;
    __syncthreads();
  }
  bbase[t] = sd[t] - v;
  if (t == 255) bbase[256] = sd[255];  // == N_EDGES
  if (t < EP_PAD) ep[N_EDGES + t] = make_int2(0, 0);
}

__global__ __launch_bounds__(1024) void p2_part_k(
    const int* __restrict__ row, const int* __restrict__ col,
    const float* __restrict__ val, const int* __restrict__ h2d,
    const int* __restrict__ bbase, int2* __restrict__ pcv,
    unsigned short* __restrict__ plr) {
  __shared__ int cur[NBUK];
  const int i = blockIdx.x, t = threadIdx.x;
  if (t < NBUK) cur[t] = bbase[t] + h2d[i * NBUK + t];
  __syncthreads();
  const int e0 = i * EPP, e1 = e0 + EPP;
  for (int e = e0 + t; e < e1; e += 1024) {
    int r = row[e];
    int b = r / RPB;
    int p = atomicAdd(&cur[b], 1);
    pcv[p] = make_int2(col[e], __float_as_int(val[e]));
    plr[p] = (unsigned short)(r - b * RPB);
  }
}

__global__ __launch_bounds__(1024) void p3_fine_k(const int2* __restrict__ pcv,
                                                  const unsigned short* __restrict__ plr,
                                                  const int* __restrict__ bbase,
                                                  int* __restrict__ rp,
                                                  int2* __restrict__ ep) {
  __shared__ int cnt[RPB];
  __shared__ int cur[RPB];
  const int b = blockIdx.x, t = threadIdx.x;
  const int ebeg = bbase[b], eend = bbase[b + 1];
  const int r0 = b * RPB;
  const int nloc = min(RPB, N_NODES - r0);

  for (int i = t; i < RPB; i += 1024) cnt[i] = 0;
  __syncthreads();
  for (int j = ebeg + t; j < eend; j += 1024) atomicAdd(&cnt[plr[j]], 1);
  __syncthreads();

  if (t < 64) {  // exclusive scan of cnt[0..390] by wave 0
    const int base_ = t * 7;
    int v[7], s = 0;
#pragma unroll
    for (int k = 0; k < 7; ++k) {
      int idx = base_ + k;
      v[k] = (idx < RPB) ? cnt[idx] : 0;
      s += v[k];
    }
    int incl = s;
#pragma unroll
    for (int off = 1; off < 64; off <<= 1) {
      int y = __shfl_up(incl, off);
      if (t >= off) incl += y;
    }
    int run = incl - s;
#pragma unroll
    for (int k = 0; k < 7; ++k) {
      int idx = base_ + k;
      if (idx < RPB) cnt[idx] = run;
      run += v[k];
    }
  }
  __syncthreads();

  for (int i = t; i < nloc; i += 1024) {
    rp[r0 + i] = ebeg + cnt[i];
    cur[i] = cnt[i];
  }
  if (b == 0 && t == 0) rp[N_NODES] = N_EDGES;
  __syncthreads();

  for (int j = ebeg + t; j < eend; j += 1024) {
    int lr = plr[j];
    int p = atomicAdd(&cur[lr], 1);
    ep[ebeg + p] = pcv[j];
  }
}

// ---------------------------------------------------------------------------
// MFMA GEMM layer-1: S[N,64](bf16) = x[N,128](fp32->bf16) @ W1[128,64].
// Persistent waves, grid-stride over 16-row tiles; B frags preloaded once.
// ---------------------------------------------------------------------------
__global__ __launch_bounds__(256) void gemm_l1(const float* __restrict__ X,
                                               const float* __restrict__ W,
                                               unsigned short* __restrict__ S) {
  const int lane = threadIdx.x & 63;
  const int quad = lane >> 4;
  const int m = lane & 15;

  short8 bf[4][4];
#pragma unroll
  for (int t = 0; t < 4; ++t)
#pragma unroll
    for (int h = 0; h < 4; ++h)
#pragma unroll
      for (int j = 0; j < 8; ++j)
        bf[t][h][j] = f2bs(W[(h * 32 + quad * 8 + j) * 64 + t * 16 + m]);

  const int wid = blockIdx.x * 4 + (threadIdx.x >> 6);
  for (int tile = wid; tile < NTILES; tile += gridDim.x * 4) {
    const int r0 = tile * 16;
    const float* xr = X + (size_t)(r0 + m) * 128;
    short8 af[4];
#pragma unroll
    for (int h = 0; h < 4; ++h) {
      const float* p = xr + h * 32 + quad * 8;
      float4 a = *(const float4*)p;
      float4 b = *(const float4*)(p + 4);
      af[h][0] = f2bs(a.x); af[h][1] = f2bs(a.y);
      af[h][2] = f2bs(a.z); af[h][3] = f2bs(a.w);
      af[h][4] = f2bs(b.x); af[h][5] = f2bs(b.y);
      af[h][6] = f2bs(b.z); af[h][7] = f2bs(b.w);
    }
#pragma unroll
    for (int t = 0; t < 4; ++t) {
      floatx4 acc = {0.0f, 0.0f, 0.0f, 0.0f};
#pragma unroll
      for (int h = 0; h < 4; ++h)
        acc = __builtin_amdgcn_mfma_f32_16x16x32_bf16(af[h], bf[t][h], acc, 0, 0, 0);
#pragma unroll
      for (int r = 0; r < 4; ++r)
        S[(size_t)(r0 + quad * 4 + r) * 64 + t * 16 + m] = (unsigned short)f2bs(acc[r]);
    }
  }
}

// ---------------------------------------------------------------------------
// Fused SpMM + next-layer MFMA GEMM. Block = 512 threads = 8 waves = 16 nodes
// (one MFMA M-tile). Gather: wave per node pair, 8-lane row groups (R7,
// proven). Epilogue: h rows -> LDS (stride 72 shorts: quad-reads land 2-way
// bank-aliased = free), barrier, wave 0 applies Wn via 8 MFMAs -> Sout.
// h also stored to Hb (bf16) as the residual source two layers later.
// Bit-identical to the unfused spmm8_k + gemm_bf pipeline.
// ---------------------------------------------------------------------------
template <bool RES, int COLS>
__global__ __launch_bounds__(512) void spmm_fused_k(
    const unsigned short* __restrict__ S, const int2* __restrict__ ep,
    const int* __restrict__ rp, const float* __restrict__ bias,
    unsigned short* __restrict__ Hb,   // residual source & dest (bf16)
    const float* __restrict__ Wn,      // next-layer weight [64,COLS]
    unsigned short* __restrict__ Sout) {
  __shared__ alignas(16) unsigned short hl[16 * 72];

  const int tid = threadIdx.x;
  const int lane = tid & 63;
  const int wv = tid >> 6;  // 0..7
  const int og = lane >> 3;
  const int i8 = lane & 7;
  const int sg = og & 3;
  const bool isB = og >= 4;

  const int blk0 = blockIdx.x * 16;  // first node of this block
  const int nodeA = blk0 + wv * 2;
  const int sA = rp[nodeA], sB = rp[nodeA + 1], eB = rp[nodeA + 2];
  const int myNode = nodeA + (isB ? 1 : 0);
  const int myBeg = isB ? sB : sA;
  const int myEnd = isB ? eB : sB;
  const int iters = (max(sB - sA, eB - sB) + 7) >> 3;

  // Wave 0 preloads next-layer B fragments before the gather loop
  short8 bfrag[4][2];
  if (wv == 0) {
    const int quad = lane >> 4, m = lane & 15;
#pragma unroll
    for (int t = 0; t < 4; ++t) {
      const int cc = t * 16 + m;
#pragma unroll
      for (int h = 0; h < 2; ++h)
#pragma unroll
        for (int j = 0; j < 8; ++j)
          bfrag[t][h][j] = (COLS == 64 || cc < COLS)
                               ? f2bs(Wn[(h * 32 + quad * 8 + j) * COLS + cc])
                               : (short)0;
    }
  }

  // Gather (R7 geometry: one wave-instr = 8 rows; ep prefetched)
  float a[8] = {0, 0, 0, 0, 0, 0, 0, 0};
  int e = myBeg + sg;
  int2 q0 = ep[e], q1 = ep[e + 4];
  for (int it = 0; it < iters; ++it) {
    int2 n0 = ep[e + 8], n1 = ep[e + 12];  // pad covers overrun
    float v0 = (e < myEnd) ? __int_as_float(q0.y) : 0.0f;
    float v1 = (e + 4 < myEnd) ? __int_as_float(q1.y) : 0.0f;
    ushort8v s0 = *(const ushort8v*)(S + ((size_t)q0.x * 64 + i8 * 8));
    ushort8v s1 = *(const ushort8v*)(S + ((size_t)q1.x * 64 + i8 * 8));
#pragma unroll
    for (int j = 0; j < 8; ++j) a[j] = fmaf(v0, bfbits(s0[j]), a[j]);
#pragma unroll
    for (int j = 0; j < 8; ++j) a[j] = fmaf(v1, bfbits(s1[j]), a[j]);
    q0 = n0; q1 = n1; e += 8;
  }

#pragma unroll
  for (int j = 0; j < 8; ++j) {
    a[j] += __shfl_xor(a[j], 8);
    a[j] += __shfl_xor(a[j], 16);
  }

  if (sg == 0) {  // og==0 (node A) / og==4 (node B): lane holds feats i8*8..+7
    float4 b0 = ((const float4*)bias)[i8 * 2];
    float4 b1 = ((const float4*)bias)[i8 * 2 + 1];
    float h[8];
    h[0] = fmaxf(a[0] + b0.x, 0.0f); h[1] = fmaxf(a[1] + b0.y, 0.0f);
    h[2] = fmaxf(a[2] + b0.z, 0.0f); h[3] = fmaxf(a[3] + b0.w, 0.0f);
    h[4] = fmaxf(a[4] + b1.x, 0.0f); h[5] = fmaxf(a[5] + b1.y, 0.0f);
    h[6] = fmaxf(a[6] + b1.z, 0.0f); h[7] = fmaxf(a[7] + b1.w, 0.0f);
    if (RES) {
      ushort8v r = ((const ushort8v*)Hb)[(size_t)myNode * 8 + i8];
#pragma unroll
      for (int j = 0; j < 8; ++j) h[j] += bfbits(r[j]);
    }
    ushort8v hb;
#pragma unroll
    for (int j = 0; j < 8; ++j) hb[j] = (unsigned short)f2bs(h[j]);
    ((ushort8v*)Hb)[(size_t)myNode * 8 + i8] = hb;
    const int ln = myNode - blk0;  // 0..15
    *(ushort8v*)&hl[ln * 72 + i8 * 8] = hb;
  }
  __syncthreads();

  if (wv == 0) {  // 16x64 MFMA tile: Sout[blk0..blk0+15] = h @ Wn
    const int quad = lane >> 4, m = lane & 15;
    short8 a0 = *(const short8*)&hl[m * 72 + quad * 8];
    short8 a1 = *(const short8*)&hl[m * 72 + 32 + quad * 8];
#pragma unroll
    for (int t = 0; t < 4; ++t) {
      floatx4 acc = {0.0f, 0.0f, 0.0f, 0.0f};
      acc = __builtin_amdgcn_mfma_f32_16x16x32_bf16(a0, bfrag[t][0], acc, 0, 0, 0);
      acc = __builtin_amdgcn_mfma_f32_16x16x32_bf16(a1, bfrag[t][1], acc, 0, 0, 0);
#pragma unroll
      for (int r = 0; r < 4; ++r)
        Sout[(size_t)(blk0 + quad * 4 + r) * 64 + t * 16 + m] =
            (unsigned short)f2bs(acc[r]);
    }
  }
}

// Final: gather on 64-padded S40 + bias + log_softmax (R7 geometry).
__global__ __launch_bounds__(256) void spmm_final_k(
    const unsigned short* __restrict__ S, const int2* __restrict__ ep,
    const int* __restrict__ rp, const float* __restrict__ b2,
    float* __restrict__ out) {
  const int lane = threadIdx.x & 63;
  const int og = lane >> 3;
  const int i8 = lane & 7;
  const int sg = og & 3;
  const bool isB = og >= 4;
  const int pair = blockIdx.x * 4 + (threadIdx.x >> 6);
  const int nodeA = pair * 2;
  const int sA = rp[nodeA], sB = rp[nodeA + 1], eB = rp[nodeA + 2];
  const int myNode = nodeA + (isB ? 1 : 0);
  const int myBeg = isB ? sB : sA;
  const int myEnd = isB ? eB : sB;
  const int iters = (max(sB - sA, eB - sB) + 7) >> 3;

  float a[8] = {0, 0, 0, 0, 0, 0, 0, 0};
  int e = myBeg + sg;
  int2 q0 = ep[e], q1 = ep[e + 4];
  for (int it = 0; it < iters; ++it) {
    int2 n0 = ep[e + 8], n1 = ep[e + 12];
    float v0 = (e < myEnd) ? __int_as_float(q0.y) : 0.0f;
    float v1 = (e + 4 < myEnd) ? __int_as_float(q1.y) : 0.0f;
    ushort8v s0 = *(const ushort8v*)(S + ((size_t)q0.x * 64 + i8 * 8));
    ushort8v s1 = *(const ushort8v*)(S + ((size_t)q1.x * 64 + i8 * 8));
#pragma unroll
    for (int j = 0; j < 8; ++j) a[j] = fmaf(v0, bfbits(s0[j]), a[j]);
#pragma unroll
    for (int j = 0; j < 8; ++j) a[j] = fmaf(v1, bfbits(s1[j]), a[j]);
    q0 = n0; q1 = n1; e += 8;
  }

#pragma unroll
  for (int j = 0; j < 8; ++j) {
    a[j] += __shfl_xor(a[j], 8);
    a[j] += __shfl_xor(a[j], 16);
  }

  // lane i8 holds feats i8*8..+7; valid class lanes: i8 < 5 (5*8 = 40)
  const bool valid = (i8 < 5);
  float l[8];
  float mx = -INFINITY;
  if (valid) {
    float4 c0 = ((const float4*)b2)[i8 * 2];
    float4 c1 = ((const float4*)b2)[i8 * 2 + 1];
    l[0] = a[0] + c0.x; l[1] = a[1] + c0.y; l[2] = a[2] + c0.z; l[3] = a[3] + c0.w;
    l[4] = a[4] + c1.x; l[5] = a[5] + c1.y; l[6] = a[6] + c1.z; l[7] = a[7] + c1.w;
#pragma unroll
    for (int j = 0; j < 8; ++j) mx = fmaxf(mx, l[j]);
  }
#pragma unroll
  for (int off = 1; off < 8; off <<= 1) mx = fmaxf(mx, __shfl_xor(mx, off));
  float sum = 0.0f;
  if (valid) {
#pragma unroll
    for (int j = 0; j < 8; ++j) sum += expf(l[j] - mx);
  }
#pragma unroll
  for (int off = 1; off < 8; off <<= 1) sum += __shfl_xor(sum, off);

  if (sg == 0 && valid) {
    float lg = mx + logf(sum);
    ((float4*)out)[(size_t)myNode * 10 + i8 * 2] =
        make_float4(l[0] - lg, l[1] - lg, l[2] - lg, l[3] - lg);
    ((float4*)out)[(size_t)myNode * 10 + i8 * 2 + 1] =
        make_float4(l[4] - lg, l[5] - lg, l[6] - lg, l[7] - lg);
  }
}

// ---------------------------------------------------------------------------
extern "C" void kernel_launch(void* const* d_in, const int* in_sizes, int n_in,
                              void* d_out, int out_size, void* d_ws, size_t ws_size,
                              hipStream_t stream) {
  const float* x    = (const float*)d_in[0];
  const int*   erow = (const int*)d_in[1];
  const int*   ecol = (const int*)d_in[2];
  const float* eval = (const float*)d_in[3];
  const float* W1   = (const float*)d_in[4];
  const float* b1   = (const float*)d_in[5];
  const float* Wm   = (const float*)d_in[6];
  const float* bm   = (const float*)d_in[7];
  const float* W2   = (const float*)d_in[8];
  const float* b2   = (const float*)d_in[9];
  float* out = (float*)d_out;

  // Workspace (~82 MB). pcv/plr dead after p3_fine_k -> Sa aliases them.
  char* ws = (char*)d_ws;
  size_t off = 0;
  auto alloc = [&](size_t bytes) {
    void* p = ws + off;
    off = (off + bytes + 255) & ~(size_t)255;
    return p;
  };
  int*  rp    = (int*)alloc((N_NODES + 1) * sizeof(int));
  int*  h2d   = (int*)alloc((size_t)NBUK * NBUK * sizeof(int));
  int*  btot  = (int*)alloc(NBUK * sizeof(int));
  int*  bbase = (int*)alloc((NBUK + 1) * sizeof(int));
  int2* ep    = (int2*)alloc((size_t)(N_EDGES + EP_PAD) * sizeof(int2));
  char* U     = (char*)alloc((size_t)N_EDGES * sizeof(int2) +
                             (((size_t)N_EDGES * sizeof(unsigned short) + 255) & ~(size_t)255));
  int2* pcv = (int2*)U;
  unsigned short* plr = (unsigned short*)(U + (size_t)N_EDGES * sizeof(int2));
  unsigned short* Sa = (unsigned short*)U;  // alias: live only after CSR build
  unsigned short* Sb = (unsigned short*)alloc((size_t)N_NODES * 64 * sizeof(unsigned short));
  unsigned short* B0 = (unsigned short*)alloc((size_t)N_NODES * 64 * sizeof(unsigned short));
  unsigned short* B1 = (unsigned short*)alloc((size_t)N_NODES * 64 * sizeof(unsigned short));

  const int FUSE_GRID = N_NODES / 16;   // 6250 blocks x 8 waves x 2 nodes
  const int FINAL_GRID = N_NODES / 8;   // 12500 blocks x 4 waves x 2 nodes
  const int GEMM_GRID = 512;            // persistent

  // CSR build
  p0_hist_k<<<NBUK, 1024, 0, stream>>>(erow, h2d);
  k1_scanb_k<<<NBUK, 256, 0, stream>>>(h2d, btot);
  k2_scanbase_k<<<1, 256, 0, stream>>>(btot, bbase, ep);
  p2_part_k<<<NBUK, 1024, 0, stream>>>(erow, ecol, eval, h2d, bbase, pcv, plr);
  p3_fine_k<<<NBUK, 1024, 0, stream>>>(pcv, plr, bbase, rp, ep);

  // S1 = x@W1
  gemm_l1<<<GEMM_GRID, 256, 0, stream>>>(x, W1, Sa);

  // L1: h1 = relu(A Sa + b1) -> B0 ; Sb = h1@Wm[0]
  spmm_fused_k<false, 64><<<FUSE_GRID, 512, 0, stream>>>(Sa, ep, rp, b1, B0, Wm, Sb);
  // L2: h2 -> B1 ; Sa = h2@Wm[1]
  spmm_fused_k<false, 64><<<FUSE_GRID, 512, 0, stream>>>(Sb, ep, rp, bm, B1, Wm + 4096, Sa);
  // L3: h3 = relu(A Sa + bm1) + h1(B0) -> B0 ; Sb = h3@Wm[2]
  spmm_fused_k<true, 64><<<FUSE_GRID, 512, 0, stream>>>(Sa, ep, rp, bm + 64, B0, Wm + 2 * 4096, Sb);
  // L4: h4 = ... + h2(B1) -> B1 ; Sa = h4@Wm[3]
  spmm_fused_k<true, 64><<<FUSE_GRID, 512, 0, stream>>>(Sb, ep, rp, bm + 128, B1, Wm + 3 * 4096, Sa);
  // L5: h5 = ... + h3(B0) -> B0 ; Sb = h5@Wm[4]
  spmm_fused_k<true, 64><<<FUSE_GRID, 512, 0, stream>>>(Sa, ep, rp, bm + 192, B0, Wm + 4 * 4096, Sb);
  // L6: h6 = ... + h4(B1) -> B1 ; Sa = h6@Wm[5]
  spmm_fused_k<true, 64><<<FUSE_GRID, 512, 0, stream>>>(Sb, ep, rp, bm + 256, B1, Wm + 5 * 4096, Sa);
  // L7: h7 = ... + h5(B0) -> B0 ; Sb = h7@W2 (64-padded, cols 40..63 zero)
  spmm_fused_k<true, 40><<<FUSE_GRID, 512, 0, stream>>>(Sa, ep, rp, bm + 320, B0, W2, Sb);

  // out = log_softmax(A Sb + b2)
  spmm_final_k<<<FINAL_GRID, 256, 0, stream>>>(Sb, ep, rp, b2, out);
}

// Round 9
// 492.980 us; speedup vs baseline: 1.2007x; 1.2007x over previous
//
#include <hip/hip_runtime.h>
#include <hip/hip_bf16.h>
#include <math.h>

// Problem constants (fixed by the reference)
#define N_NODES 100000
#define N_EDGES 1600000
#define NFEAT 128
#define NHID  64
#define NCLASS 40
#define NL 6

#define NBUK 256          // coarse buckets for CSR build
#define RPB  391          // rows per bucket (391*256 >= 100000)
#define EPP  (N_EDGES / NBUK)  // 6250 edges per partition block (exact)
#define EP_PAD 256        // zero-padded ep tail for pipelined spmm reads
#define NTILES (N_NODES / 16)  // 6250 row-tiles, exact

typedef __attribute__((ext_vector_type(8))) short short8;
typedef __attribute__((ext_vector_type(8))) unsigned short ushort8v;
typedef __attribute__((ext_vector_type(4))) float floatx4;

__device__ __forceinline__ float bfbits(unsigned short u) {
  return __uint_as_float((unsigned int)u << 16);
}
__device__ __forceinline__ short f2bs(float f) {
  __hip_bfloat16 h = __float2bfloat16(f);  // RNE
  return *reinterpret_cast<short*>(&h);
}

// ---------------------------------------------------------------------------
// CSR build (R4 full-line-write design, 1024-thread blocks — proven)
// ---------------------------------------------------------------------------
__global__ __launch_bounds__(1024) void p0_hist_k(const int* __restrict__ row,
                                                  int* __restrict__ h2d) {
  __shared__ int h[NBUK];
  const int i = blockIdx.x, t = threadIdx.x;
  if (t < NBUK) h[t] = 0;
  __syncthreads();
  const int e0 = i * EPP, e1 = e0 + EPP;
  for (int e = e0 + t; e < e1; e += 1024) atomicAdd(&h[row[e] / RPB], 1);
  __syncthreads();
  if (t < NBUK) h2d[i * NBUK + t] = h[t];  // coalesced
}

__global__ __launch_bounds__(256) void k1_scanb_k(int* __restrict__ h2d,
                                                  int* __restrict__ btot) {
  __shared__ int sd[256];
  const int b = blockIdx.x, t = threadIdx.x;
  int v = h2d[t * NBUK + b];
  sd[t] = v;
  __syncthreads();
  for (int off = 1; off < 256; off <<= 1) {
    int a = (t >= off) ? sd[t - off] : 0;
    __syncthreads();
    sd[t] += a;
    __syncthreads();
  }
  h2d[t * NBUK + b] = sd[t] - v;  // exclusive prefix within bucket
  if (t == 255) btot[b] = sd[255];
}

__global__ __launch_bounds__(256) void k2_scanbase_k(const int* __restrict__ btot,
                                                     int* __restrict__ bbase,
                                                     int2* __restrict__ ep) {
  __shared__ int sd[256];
  const int t = threadIdx.x;
  int v = btot[t];
  sd[t] = v;
  __syncthreads();
  for (int off = 1; off < 256; off <<= 1) {
    int a = (t >= off) ? sd[t - off] : 0;
    __syncthreads();
    sd[t] += a;
    __syncthreads();
  }
  bbase[t] = sd[t] - v;
  if (t == 255) bbase[256] = sd[255];  // == N_EDGES
  if (t < EP_PAD) ep[N_EDGES + t] = make_int2(0, 0);
}

__global__ __launch_bounds__(1024) void p2_part_k(
    const int* __restrict__ row, const int* __restrict__ col,
    const float* __restrict__ val, const int* __restrict__ h2d,
    const int* __restrict__ bbase, int2* __restrict__ pcv,
    unsigned short* __restrict__ plr) {
  __shared__ int cur[NBUK];
  const int i = blockIdx.x, t = threadIdx.x;
  if (t < NBUK) cur[t] = bbase[t] + h2d[i * NBUK + t];
  __syncthreads();
  const int e0 = i * EPP, e1 = e0 + EPP;
  for (int e = e0 + t; e < e1; e += 1024) {
    int r = row[e];
    int b = r / RPB;
    int p = atomicAdd(&cur[b], 1);
    pcv[p] = make_int2(col[e], __float_as_int(val[e]));
    plr[p] = (unsigned short)(r - b * RPB);
  }
}

__global__ __launch_bounds__(1024) void p3_fine_k(const int2* __restrict__ pcv,
                                                  const unsigned short* __restrict__ plr,
                                                  const int* __restrict__ bbase,
                                                  int* __restrict__ rp,
                                                  int2* __restrict__ ep) {
  __shared__ int cnt[RPB];
  __shared__ int cur[RPB];
  const int b = blockIdx.x, t = threadIdx.x;
  const int ebeg = bbase[b], eend = bbase[b + 1];
  const int r0 = b * RPB;
  const int nloc = min(RPB, N_NODES - r0);

  for (int i = t; i < RPB; i += 1024) cnt[i] = 0;
  __syncthreads();
  for (int j = ebeg + t; j < eend; j += 1024) atomicAdd(&cnt[plr[j]], 1);
  __syncthreads();

  if (t < 64) {  // exclusive scan of cnt[0..390] by wave 0
    const int base_ = t * 7;
    int v[7], s = 0;
#pragma unroll
    for (int k = 0; k < 7; ++k) {
      int idx = base_ + k;
      v[k] = (idx < RPB) ? cnt[idx] : 0;
      s += v[k];
    }
    int incl = s;
#pragma unroll
    for (int off = 1; off < 64; off <<= 1) {
      int y = __shfl_up(incl, off);
      if (t >= off) incl += y;
    }
    int run = incl - s;
#pragma unroll
    for (int k = 0; k < 7; ++k) {
      int idx = base_ + k;
      if (idx < RPB) cnt[idx] = run;
      run += v[k];
    }
  }
  __syncthreads();

  for (int i = t; i < nloc; i += 1024) {
    rp[r0 + i] = ebeg + cnt[i];
    cur[i] = cnt[i];
  }
  if (b == 0 && t == 0) rp[N_NODES] = N_EDGES;
  __syncthreads();

  for (int j = ebeg + t; j < eend; j += 1024) {
    int lr = plr[j];
    int p = atomicAdd(&cur[lr], 1);
    ep[ebeg + p] = pcv[j];
  }
}

// ---------------------------------------------------------------------------
// MFMA GEMM layer-1: S[N,64](bf16) = x[N,128](fp32->bf16) @ W1[128,64].
// Persistent waves, grid-stride over 16-row tiles; B frags preloaded once.
// ---------------------------------------------------------------------------
__global__ __launch_bounds__(256) void gemm_l1(const float* __restrict__ X,
                                               const float* __restrict__ W,
                                               unsigned short* __restrict__ S) {
  const int lane = threadIdx.x & 63;
  const int quad = lane >> 4;
  const int m = lane & 15;

  short8 bf[4][4];
#pragma unroll
  for (int t = 0; t < 4; ++t)
#pragma unroll
    for (int h = 0; h < 4; ++h)
#pragma unroll
      for (int j = 0; j < 8; ++j)
        bf[t][h][j] = f2bs(W[(h * 32 + quad * 8 + j) * 64 + t * 16 + m]);

  const int wid = blockIdx.x * 4 + (threadIdx.x >> 6);
  for (int tile = wid; tile < NTILES; tile += gridDim.x * 4) {
    const int r0 = tile * 16;
    const float* xr = X + (size_t)(r0 + m) * 128;
    short8 af[4];
#pragma unroll
    for (int h = 0; h < 4; ++h) {
      const float* p = xr + h * 32 + quad * 8;
      float4 a = *(const float4*)p;
      float4 b = *(const float4*)(p + 4);
      af[h][0] = f2bs(a.x); af[h][1] = f2bs(a.y);
      af[h][2] = f2bs(a.z); af[h][3] = f2bs(a.w);
      af[h][4] = f2bs(b.x); af[h][5] = f2bs(b.y);
      af[h][6] = f2bs(b.z); af[h][7] = f2bs(b.w);
    }
#pragma unroll
    for (int t = 0; t < 4; ++t) {
      floatx4 acc = {0.0f, 0.0f, 0.0f, 0.0f};
#pragma unroll
      for (int h = 0; h < 4; ++h)
        acc = __builtin_amdgcn_mfma_f32_16x16x32_bf16(af[h], bf[t][h], acc, 0, 0, 0);
#pragma unroll
      for (int r = 0; r < 4; ++r)
        S[(size_t)(r0 + quad * 4 + r) * 64 + t * 16 + m] = (unsigned short)f2bs(acc[r]);
    }
  }
}

// MFMA GEMM mid/final: S[N,64](bf16) = Hb[N,64](bf16) @ W[64,COLS](fp32).
template <int COLS>
__global__ __launch_bounds__(256) void gemm_bf(const unsigned short* __restrict__ Hb,
                                               const float* __restrict__ W,
                                               unsigned short* __restrict__ S) {
  const int lane = threadIdx.x & 63;
  const int quad = lane >> 4;
  const int m = lane & 15;

  short8 bf[4][2];
#pragma unroll
  for (int t = 0; t < 4; ++t) {
    const int cc = t * 16 + m;
#pragma unroll
    for (int h = 0; h < 2; ++h)
#pragma unroll
      for (int j = 0; j < 8; ++j)
        bf[t][h][j] = (COLS == 64 || cc < COLS)
                          ? f2bs(W[(h * 32 + quad * 8 + j) * COLS + cc])
                          : (short)0;
  }

  const int wid = blockIdx.x * 4 + (threadIdx.x >> 6);
  for (int tile = wid; tile < NTILES; tile += gridDim.x * 4) {
    const int r0 = tile * 16;
    const unsigned short* hr = Hb + (size_t)(r0 + m) * 64 + quad * 8;
    short8 af0 = *(const short8*)hr;
    short8 af1 = *(const short8*)(hr + 32);
#pragma unroll
    for (int t = 0; t < 4; ++t) {
      floatx4 acc = {0.0f, 0.0f, 0.0f, 0.0f};
      acc = __builtin_amdgcn_mfma_f32_16x16x32_bf16(af0, bf[t][0], acc, 0, 0, 0);
      acc = __builtin_amdgcn_mfma_f32_16x16x32_bf16(af1, bf[t][1], acc, 0, 0, 0);
#pragma unroll
      for (int r = 0; r < 4; ++r)
        S[(size_t)(r0 + quad * 4 + r) * 64 + t * 16 + m] = (unsigned short)f2bs(acc[r]);
    }
  }
}

// ---------------------------------------------------------------------------
// SpMM, 8-lanes-per-row geometry + 2-stage software pipeline. Wave per NODE
// PAIR: og=0..3 -> node A, og=4..7 -> node B; one wave-instr gathers 8 rows.
// Pipeline: ep loads 2 iters ahead, S-gathers 1 iter ahead -> FMAs consume
// data loaded a full iteration earlier (no per-iter vmcnt stall). Same
// instruction count & FMA order as R7 (bit-identical numerics).
// ---------------------------------------------------------------------------
template <bool RES>
__global__ __launch_bounds__(256) void spmm8_k(
    const unsigned short* __restrict__ S, const int2* __restrict__ ep,
    const int* __restrict__ rp, const float* __restrict__ bias,
    unsigned short* __restrict__ Hbout) {  // Hbout doubles as residual source
  const int lane = threadIdx.x & 63;
  const int og = lane >> 3;
  const int i8 = lane & 7;
  const int sg = og & 3;
  const bool isB = og >= 4;
  const int pair = blockIdx.x * 4 + (threadIdx.x >> 6);
  const int nodeA = pair * 2;
  const int sA = rp[nodeA], sB = rp[nodeA + 1], eB = rp[nodeA + 2];
  const int myNode = nodeA + (isB ? 1 : 0);
  const int myBeg = isB ? sB : sA;
  const int myEnd = isB ? eB : sB;
  const int iters = (max(sB - sA, eB - sB) + 7) >> 3;

  float a[8] = {0, 0, 0, 0, 0, 0, 0, 0};
  // Pipeline prologue: ep+gather for iter 0, ep for iter 1 (pad covers overrun)
  int e = myBeg + sg;            // ep-stage slot base
  int ec = e;                    // fma-stage slot base
  int2 q0 = ep[e], q1 = ep[e + 4];
  int2 n0 = ep[e + 8], n1 = ep[e + 12];
  ushort8v s0 = *(const ushort8v*)(S + ((size_t)q0.x * 64 + i8 * 8));
  ushort8v s1 = *(const ushort8v*)(S + ((size_t)q1.x * 64 + i8 * 8));
  e += 8;

  for (int it = 0; it < iters; ++it) {
    int2 m0 = ep[e + 8], m1 = ep[e + 12];  // ep for it+2
    ushort8v t0 = *(const ushort8v*)(S + ((size_t)n0.x * 64 + i8 * 8));  // it+1
    ushort8v t1 = *(const ushort8v*)(S + ((size_t)n1.x * 64 + i8 * 8));
    float v0 = (ec < myEnd) ? __int_as_float(q0.y) : 0.0f;
    float v1 = (ec + 4 < myEnd) ? __int_as_float(q1.y) : 0.0f;
#pragma unroll
    for (int j = 0; j < 8; ++j) a[j] = fmaf(v0, bfbits(s0[j]), a[j]);
#pragma unroll
    for (int j = 0; j < 8; ++j) a[j] = fmaf(v1, bfbits(s1[j]), a[j]);
    q0 = n0; q1 = n1; n0 = m0; n1 = m1; s0 = t0; s1 = t1;
    ec += 8; e += 8;
  }

#pragma unroll
  for (int j = 0; j < 8; ++j) {
    a[j] += __shfl_xor(a[j], 8);
    a[j] += __shfl_xor(a[j], 16);
  }

  if (sg == 0) {  // og==0 (node A) / og==4 (node B): lane holds feats i8*8..+7
    float4 b0 = ((const float4*)bias)[i8 * 2];
    float4 b1 = ((const float4*)bias)[i8 * 2 + 1];
    float h[8];
    h[0] = fmaxf(a[0] + b0.x, 0.0f); h[1] = fmaxf(a[1] + b0.y, 0.0f);
    h[2] = fmaxf(a[2] + b0.z, 0.0f); h[3] = fmaxf(a[3] + b0.w, 0.0f);
    h[4] = fmaxf(a[4] + b1.x, 0.0f); h[5] = fmaxf(a[5] + b1.y, 0.0f);
    h[6] = fmaxf(a[6] + b1.z, 0.0f); h[7] = fmaxf(a[7] + b1.w, 0.0f);
    if (RES) {
      ushort8v r = ((const ushort8v*)Hbout)[(size_t)myNode * 8 + i8];
#pragma unroll
      for (int j = 0; j < 8; ++j) h[j] += bfbits(r[j]);
    }
    ushort8v hb;
#pragma unroll
    for (int j = 0; j < 8; ++j) hb[j] = (unsigned short)f2bs(h[j]);
    ((ushort8v*)Hbout)[(size_t)myNode * 8 + i8] = hb;
  }
}

// Final: same pipelined gather on 64-padded S40 + bias + log_softmax.
__global__ __launch_bounds__(256) void spmm_final_k(
    const unsigned short* __restrict__ S, const int2* __restrict__ ep,
    const int* __restrict__ rp, const float* __restrict__ b2,
    float* __restrict__ out) {
  const int lane = threadIdx.x & 63;
  const int og = lane >> 3;
  const int i8 = lane & 7;
  const int sg = og & 3;
  const bool isB = og >= 4;
  const int pair = blockIdx.x * 4 + (threadIdx.x >> 6);
  const int nodeA = pair * 2;
  const int sA = rp[nodeA], sB = rp[nodeA + 1], eB = rp[nodeA + 2];
  const int myNode = nodeA + (isB ? 1 : 0);
  const int myBeg = isB ? sB : sA;
  const int myEnd = isB ? eB : sB;
  const int iters = (max(sB - sA, eB - sB) + 7) >> 3;

  float a[8] = {0, 0, 0, 0, 0, 0, 0, 0};
  int e = myBeg + sg;
  int ec = e;
  int2 q0 = ep[e], q1 = ep[e + 4];
  int2 n0 = ep[e + 8], n1 = ep[e + 12];
  ushort8v s0 = *(const ushort8v*)(S + ((size_t)q0.x * 64 + i8 * 8));
  ushort8v s1 = *(const ushort8v*)(S + ((size_t)q1.x * 64 + i8 * 8));
  e += 8;

  for (int it = 0; it < iters; ++it) {
    int2 m0 = ep[e + 8], m1 = ep[e + 12];
    ushort8v t0 = *(const ushort8v*)(S + ((size_t)n0.x * 64 + i8 * 8));
    ushort8v t1 = *(const ushort8v*)(S + ((size_t)n1.x * 64 + i8 * 8));
    float v0 = (ec < myEnd) ? __int_as_float(q0.y) : 0.0f;
    float v1 = (ec + 4 < myEnd) ? __int_as_float(q1.y) : 0.0f;
#pragma unroll
    for (int j = 0; j < 8; ++j) a[j] = fmaf(v0, bfbits(s0[j]), a[j]);
#pragma unroll
    for (int j = 0; j < 8; ++j) a[j] = fmaf(v1, bfbits(s1[j]), a[j]);
    q0 = n0; q1 = n1; n0 = m0; n1 = m1; s0 = t0; s1 = t1;
    ec += 8; e += 8;
  }

#pragma unroll
  for (int j = 0; j < 8; ++j) {
    a[j] += __shfl_xor(a[j], 8);
    a[j] += __shfl_xor(a[j], 16);
  }

  // lane i8 holds feats i8*8..+7; valid class lanes: i8 < 5 (5*8 = 40)
  const bool valid = (i8 < 5);
  float l[8];
  float mx = -INFINITY;
  if (valid) {
    float4 c0 = ((const float4*)b2)[i8 * 2];
    float4 c1 = ((const float4*)b2)[i8 * 2 + 1];
    l[0] = a[0] + c0.x; l[1] = a[1] + c0.y; l[2] = a[2] + c0.z; l[3] = a[3] + c0.w;
    l[4] = a[4] + c1.x; l[5] = a[5] + c1.y; l[6] = a[6] + c1.z; l[7] = a[7] + c1.w;
#pragma unroll
    for (int j = 0; j < 8; ++j) mx = fmaxf(mx, l[j]);
  }
#pragma unroll
  for (int off = 1; off < 8; off <<= 1) mx = fmaxf(mx, __shfl_xor(mx, off));
  float sum = 0.0f;
  if (valid) {
#pragma unroll
    for (int j = 0; j < 8; ++j) sum += expf(l[j] - mx);
  }
#pragma unroll
  for (int off = 1; off < 8; off <<= 1) sum += __shfl_xor(sum, off);

  if (sg == 0 && valid) {
    float lg = mx + logf(sum);
    ((float4*)out)[(size_t)myNode * 10 + i8 * 2] =
        make_float4(l[0] - lg, l[1] - lg, l[2] - lg, l[3] - lg);
    ((float4*)out)[(size_t)myNode * 10 + i8 * 2 + 1] =
        make_float4(l[4] - lg, l[5] - lg, l[6] - lg, l[7] - lg);
  }
}

// ---------------------------------------------------------------------------
extern "C" void kernel_launch(void* const* d_in, const int* in_sizes, int n_in,
                              void* d_out, int out_size, void* d_ws, size_t ws_size,
                              hipStream_t stream) {
  const float* x    = (const float*)d_in[0];
  const int*   erow = (const int*)d_in[1];
  const int*   ecol = (const int*)d_in[2];
  const float* eval = (const float*)d_in[3];
  const float* W1   = (const float*)d_in[4];
  const float* b1   = (const float*)d_in[5];
  const float* Wm   = (const float*)d_in[6];
  const float* bm   = (const float*)d_in[7];
  const float* W2   = (const float*)d_in[8];
  const float* b2   = (const float*)d_in[9];
  float* out = (float*)d_out;

  // Workspace (~68 MB). pcv/plr dead after p3_fine_k -> S aliases them.
  char* ws = (char*)d_ws;
  size_t off = 0;
  auto alloc = [&](size_t bytes) {
    void* p = ws + off;
    off = (off + bytes + 255) & ~(size_t)255;
    return p;
  };
  int*  rp    = (int*)alloc((N_NODES + 1) * sizeof(int));
  int*  h2d   = (int*)alloc((size_t)NBUK * NBUK * sizeof(int));
  int*  btot  = (int*)alloc(NBUK * sizeof(int));
  int*  bbase = (int*)alloc((NBUK + 1) * sizeof(int));
  int2* ep    = (int2*)alloc((size_t)(N_EDGES + EP_PAD) * sizeof(int2));
  char* U     = (char*)alloc((size_t)N_EDGES * sizeof(int2) +
                             (((size_t)N_EDGES * sizeof(unsigned short) + 255) & ~(size_t)255));
  int2* pcv = (int2*)U;
  unsigned short* plr = (unsigned short*)(U + (size_t)N_EDGES * sizeof(int2));
  unsigned short* S = (unsigned short*)U;  // alias: live only after CSR build
  unsigned short* B0 = (unsigned short*)alloc((size_t)N_NODES * 64 * sizeof(unsigned short));
  unsigned short* B1 = (unsigned short*)alloc((size_t)N_NODES * 64 * sizeof(unsigned short));

  const int SPMM_GRID = N_NODES / 8;  // 12500 blocks x 4 waves x 2 nodes
  const int GEMM_GRID = 512;          // persistent: 2048 waves, ~3 tiles each

  // CSR build
  p0_hist_k<<<NBUK, 1024, 0, stream>>>(erow, h2d);
  k1_scanb_k<<<NBUK, 256, 0, stream>>>(h2d, btot);
  k2_scanbase_k<<<1, 256, 0, stream>>>(btot, bbase, ep);
  p2_part_k<<<NBUK, 1024, 0, stream>>>(erow, ecol, eval, h2d, bbase, pcv, plr);
  p3_fine_k<<<NBUK, 1024, 0, stream>>>(pcv, plr, bbase, rp, ep);

  // L1: S = x@W1 ; h1 = relu(A S + b1) -> B0
  gemm_l1<<<GEMM_GRID, 256, 0, stream>>>(x, W1, S);
  spmm8_k<false><<<SPMM_GRID, 256, 0, stream>>>(S, ep, rp, b1, B0);

  // L2: S = h1@Wm0 ; h2 -> B1
  gemm_bf<64><<<GEMM_GRID, 256, 0, stream>>>(B0, Wm, S);
  spmm8_k<false><<<SPMM_GRID, 256, 0, stream>>>(S, ep, rp, bm, B1);

  // L3: h3 = relu(A (h2@Wm1) + bm1) + h1(B0) -> B0
  gemm_bf<64><<<GEMM_GRID, 256, 0, stream>>>(B1, Wm + 1 * 4096, S);
  spmm8_k<true><<<SPMM_GRID, 256, 0, stream>>>(S, ep, rp, bm + 1 * 64, B0);

  // L4: h4 = ... + h2(B1) -> B1
  gemm_bf<64><<<GEMM_GRID, 256, 0, stream>>>(B0, Wm + 2 * 4096, S);
  spmm8_k<true><<<SPMM_GRID, 256, 0, stream>>>(S, ep, rp, bm + 2 * 64, B1);

  // L5: h5 = ... + h3(B0) -> B0
  gemm_bf<64><<<GEMM_GRID, 256, 0, stream>>>(B1, Wm + 3 * 4096, S);
  spmm8_k<true><<<SPMM_GRID, 256, 0, stream>>>(S, ep, rp, bm + 3 * 64, B0);

  // L6: h6 = ... + h4(B1) -> B1
  gemm_bf<64><<<GEMM_GRID, 256, 0, stream>>>(B0, Wm + 4 * 4096, S);
  spmm8_k<true><<<SPMM_GRID, 256, 0, stream>>>(S, ep, rp, bm + 4 * 64, B1);

  // L7: h7 = ... + h5(B0) -> B0
  gemm_bf<64><<<GEMM_GRID, 256, 0, stream>>>(B1, Wm + 5 * 4096, S);
  spmm8_k<true><<<SPMM_GRID, 256, 0, stream>>>(S, ep, rp, bm + 5 * 64, B0);

  // Final: S(64-padded) = h7@W2 ; out = log_softmax(A S + b2)
  gemm_bf<40><<<GEMM_GRID, 256, 0, stream>>>(B0, W2, S);
  spmm_final_k<<<SPMM_GRID, 256, 0, stream>>>(S, ep, rp, b2, out);
}